// Round 5
// baseline (246.076 us; speedup 1.0000x reference)
//
#include <hip/hip_runtime.h>
#include <math.h>
#include <stdint.h>

// ---------------- dims ----------------
#define BETA 0.9f
#define THR 1.0f
#define T_STEPS 50
#define BN_EPS 1e-5f

#define NITEM 64          // 2 inputs x 32 batch
#define C1 16
#define L1 1981           // conv1 out length
#define L1P 1984          // padded
#define P4 495            // pooled length
#define C2 32
#define L2 493            // conv2 out length
#define L2PAD 496
#define KTOT 15872        // C2*L2PAD (padded flat dim)
#define KREAL 15776       // C2*L2
#define NFC 250
#define NPAD 256
#define KSPLIT 8
#define KRANGE 1984       // KTOT/KSPLIT
#define KSTEPS 62         // KRANGE/32
#define NKTILE 496        // KTOT/32
#define MROWS 3200        // T_STEPS*NITEM

// ---------------- workspace layout (bytes) ----------------
#define OFF_CUR1 0UL
#define OFF_POOL 8126464UL            // 64*16*1984*4
#define OFF_SPK2 34340864UL           // + 26214400
#define OFF_WT   85131264UL           // + 50*64*15872
#define OFF_PART 101384192UL          // + 496*32768 (wTf = 16252928 B)
#define OFF_COMB 127598592UL          // + 8*3200*256*4

typedef __attribute__((ext_vector_type(8))) short bf16x8;
typedef __attribute__((ext_vector_type(4))) float f32x4;

__device__ __forceinline__ uint32_t f32_to_bf16_rne(float f) {
  uint32_t u = __float_as_uint(f);
  return (u + 0x7FFFu + ((u >> 16) & 1u)) >> 16;
}

// spike bytes (bit0) -> 8 bf16 {0,1}
__device__ __forceinline__ bf16x8 frag_from_bytes(uint2 a) {
  union { uint32_t u[4]; bf16x8 v; } c;
  c.u[0] = (a.x & 1u) * 0x3F80u | ((a.x >> 8) & 1u) * 0x3F800000u;
  c.u[1] = ((a.x >> 16) & 1u) * 0x3F80u | ((a.x >> 24) & 1u) * 0x3F800000u;
  c.u[2] = (a.y & 1u) * 0x3F80u | ((a.y >> 8) & 1u) * 0x3F800000u;
  c.u[3] = ((a.y >> 16) & 1u) * 0x3F80u | ((a.y >> 24) & 1u) * 0x3F800000u;
  return c.v;
}

// ---------------- K1: fc1w [250,15776] -> wTf wave-fragment-ready bf16 hi/lo ----------------
// per k-tile (32 k's): [wv(4)][ni(4)][sel(2)][lane(64)][16B] = 32 KB
__global__ __launch_bounds__(256) void k_wt(const float* __restrict__ fc1w,
                                            uint8_t* __restrict__ wTf) {
  int kt = blockIdx.x;        // 0..495
  int n = threadIdx.x;        // 0..255
  int wv = n >> 6, ni = (n >> 4) & 3, r16 = n & 15;
  uint32_t hibuf[16], lobuf[16];
#pragma unroll 4
  for (int p = 0; p < 16; ++p) {
    uint32_t h2 = 0, l2 = 0;
#pragma unroll
    for (int e = 0; e < 2; ++e) {
      int k = kt * 32 + p * 2 + e;
      int oc = k / L2PAD;
      int pos = k - oc * L2PAD;
      float w = 0.f;
      if (pos < L2 && n < NFC) w = fc1w[n * KREAL + oc * L2 + pos];
      uint32_t hb = f32_to_bf16_rne(w);
      float hf = __uint_as_float(hb << 16);
      uint32_t lb = f32_to_bf16_rne(w - hf);
      h2 |= hb << (16 * e);
      l2 |= lb << (16 * e);
    }
    hibuf[p] = h2;
    lobuf[p] = l2;
  }
  uint8_t* tb = wTf + (size_t)kt * 32768 + wv * 8192 + ni * 2048;
#pragma unroll
  for (int kgi = 0; kgi < 4; ++kgi) {
    uint4 h; h.x = hibuf[4 * kgi]; h.y = hibuf[4 * kgi + 1]; h.z = hibuf[4 * kgi + 2]; h.w = hibuf[4 * kgi + 3];
    *reinterpret_cast<uint4*>(tb + (kgi * 16 + r16) * 16) = h;
    uint4 l; l.x = lobuf[4 * kgi]; l.y = lobuf[4 * kgi + 1]; l.z = lobuf[4 * kgi + 2]; l.w = lobuf[4 * kgi + 3];
    *reinterpret_cast<uint4*>(tb + 1024 + (kgi * 16 + r16) * 16) = l;
  }
}

// ---------------- K2: conv1 (K=80, stride4) + BN1 fold -> cur1 [64][16][1984] ----------------
__global__ __launch_bounds__(256) void k_conv1(const float* __restrict__ x1, const float* __restrict__ x2,
                                               const float* __restrict__ c1w, const float* __restrict__ c1b,
                                               const float* __restrict__ g, const float* __restrict__ bb,
                                               const float* __restrict__ mn, const float* __restrict__ vr,
                                               float* __restrict__ cur1) {
  __shared__ float xs[1104];
  int item = blockIdx.y;
  int pc = blockIdx.x;                 // 0..7
  int tid = threadIdx.x;
  const float* x = (item < 32 ? x1 : x2) + (item & 31) * 8000;
  int xoff = pc * 1024;
  for (int i = tid; i < 1100; i += 256) {
    int gi = xoff + i;
    xs[i] = (gi < 8000) ? x[gi] : 0.f;
  }
  __syncthreads();
  int p = pc * 256 + tid;
  bool pv = (p < L1);
  for (int c = 0; c < C1; ++c) {
    float s = g[c] / sqrtf(vr[c] + BN_EPS);
    float sh = (c1b[c] - mn[c]) * s + bb[c];
    const float* wr = c1w + c * 80;
    float acc = 0.f;
#pragma unroll 10
    for (int k = 0; k < 80; ++k) acc += wr[k] * xs[4 * tid + k];
    if (pv) cur1[(item * C1 + c) * L1P + p] = acc * s + sh;
  }
}

// ---------------- K3: LIF1 + maxpool4, coalesced u32 stores -> pooled_T [item][t][512][16] ----------------
__global__ __launch_bounds__(256) void k_lif1(const float* __restrict__ cur1,
                                              uint8_t* __restrict__ pooledT) {
  int item = blockIdx.y;
  int g = threadIdx.x & 3;
  int p4 = blockIdx.x * 64 + (threadIdx.x >> 2);
  if (p4 >= P4) return;
  float4 cv[4];
#pragma unroll
  for (int j = 0; j < 4; ++j)
    cv[j] = *reinterpret_cast<const float4*>(cur1 + ((size_t)item * C1 + g * 4 + j) * L1P + 4 * p4);
  float m[4][4];
#pragma unroll
  for (int j = 0; j < 4; ++j)
#pragma unroll
    for (int r = 0; r < 4; ++r) m[j][r] = 0.f;
  uint32_t* out = reinterpret_cast<uint32_t*>(pooledT + ((size_t)item * 50 * 512 + p4) * 16 + g * 4);
  for (int t = 0; t < T_STEPS; ++t) {
    uint32_t pk = 0;
#pragma unroll
    for (int j = 0; j < 4; ++j) {
      int s = 0;
#pragma unroll
      for (int r = 0; r < 4; ++r) {
        float rst = (m[j][r] > THR) ? 1.f : 0.f;
        float cvv = (r == 0) ? cv[j].x : (r == 1) ? cv[j].y : (r == 2) ? cv[j].z : cv[j].w;
        m[j][r] = BETA * m[j][r] + cvv - rst;
        s |= (m[j][r] > THR);
      }
      pk |= ((uint32_t)s) << (8 * j);
    }
    out[t * 2048] = pk;
  }
}

// ---------------- K3b: conv2 weight frags (hi/lo, BN-folded) + sh2 -> wfrag (cur1 region) ----------------
__global__ __launch_bounds__(512) void k_wc2(const float* __restrict__ c2w, const float* __restrict__ c2b,
                                             const float* __restrict__ g, const float* __restrict__ bb,
                                             const float* __restrict__ mn, const float* __restrict__ vr,
                                             uint8_t* __restrict__ wfrag) {
  int t = threadIdx.x;
  int lane = t & 63;
  int fr = t >> 6;
  int hl = fr & 1, kt = (fr >> 1) & 1, nt = fr >> 2;
  int n16 = lane & 15, kg = lane >> 4;
  int oc = nt * 16 + n16;
  float s2 = g[oc] * rsqrtf(vr[oc] + BN_EPS);
  uint32_t w[4];
#pragma unroll
  for (int i = 0; i < 4; ++i) {
    uint32_t packed = 0;
#pragma unroll
    for (int e = 0; e < 2; ++e) {
      int j = i * 2 + e;
      int k = kt * 32 + kg * 8 + j;
      int tap = k >> 4, ic = k & 15;
      float raw = (tap < 3) ? c2w[oc * 48 + ic * 3 + tap] * s2 : 0.f;
      uint32_t hb = f32_to_bf16_rne(raw);
      float hf = __uint_as_float(hb << 16);
      uint32_t lb = f32_to_bf16_rne(raw - hf);
      uint32_t v = hl ? lb : hb;
      packed |= v << (16 * e);
    }
    w[i] = packed;
  }
  uint4 uu; uu.x = w[0]; uu.y = w[1]; uu.z = w[2]; uu.w = w[3];
  *reinterpret_cast<uint4*>(wfrag + fr * 1024 + lane * 16) = uu;
  if (t < C2) {
    float s2b = g[t] * rsqrtf(vr[t] + BN_EPS);
    reinterpret_cast<float*>(wfrag + 8192)[t] = (c2b[t] - mn[t]) * s2b + bb[t];
  }
}

// ---------------- K4: conv2 via MFMA + LIF2 (mem in acc lanes) -> spk2 bytes ----------------
__global__ __launch_bounds__(256) void k_conv2(const uint8_t* __restrict__ pooledT,
                                               const uint8_t* __restrict__ wfrag,
                                               uint32_t* __restrict__ spk2) {
  int item = blockIdx.y;
  int pt = blockIdx.x;
  int tid = threadIdx.x;
  int lane = tid & 63, wv = tid >> 6;
  int r16 = lane & 15, kg = lane >> 4;
  bf16x8 bw[2][2][2];
#pragma unroll
  for (int nt = 0; nt < 2; ++nt)
#pragma unroll
    for (int kt = 0; kt < 2; ++kt)
#pragma unroll
      for (int hl = 0; hl < 2; ++hl)
        bw[nt][kt][hl] = *reinterpret_cast<const bf16x8*>(wfrag + (nt * 4 + kt * 2 + hl) * 1024 + lane * 16);
  float sh[2];
  sh[0] = reinterpret_cast<const float*>(wfrag + 8192)[r16];
  sh[1] = reinterpret_cast<const float*>(wfrag + 8192)[16 + r16];
  const uint8_t* base = pooledT + (size_t)item * 50 * 8192;
  int rowA = pt * 64 + wv * 16 + r16;
  size_t off0 = (size_t)(rowA + (kg >> 1)) * 16 + 8 * (kg & 1);   // taps 0/1
  size_t off1 = (size_t)(rowA + 2) * 16 + 8 * (kg & 1);           // tap 2 (+pad)
  uint2 na0 = *reinterpret_cast<const uint2*>(base + off0);
  uint2 na1 = *reinterpret_cast<const uint2*>(base + off1);
  float mem[2][4] = {{0.f, 0.f, 0.f, 0.f}, {0.f, 0.f, 0.f, 0.f}};
  int pos_base = pt * 64 + wv * 16 + kg * 4;
  bool dostore = pos_base < L2PAD;
  for (int t = 0; t < T_STEPS; ++t) {
    uint2 a0 = na0, a1 = na1;
    const uint8_t* nb = base + (size_t)((t + 1 < T_STEPS) ? t + 1 : t) * 8192;
    na0 = *reinterpret_cast<const uint2*>(nb + off0);
    na1 = *reinterpret_cast<const uint2*>(nb + off1);
    bf16x8 af0 = frag_from_bytes(a0);
    bf16x8 af1 = frag_from_bytes(a1);
    uint32_t st[2];
#pragma unroll
    for (int nt = 0; nt < 2; ++nt) {
      f32x4 acc = (f32x4){0.f, 0.f, 0.f, 0.f};
      acc = __builtin_amdgcn_mfma_f32_16x16x32_bf16(af0, bw[nt][0][0], acc, 0, 0, 0);
      acc = __builtin_amdgcn_mfma_f32_16x16x32_bf16(af1, bw[nt][1][0], acc, 0, 0, 0);
      acc = __builtin_amdgcn_mfma_f32_16x16x32_bf16(af0, bw[nt][0][1], acc, 0, 0, 0);
      acc = __builtin_amdgcn_mfma_f32_16x16x32_bf16(af1, bw[nt][1][1], acc, 0, 0, 0);
      uint32_t packed = 0;
#pragma unroll
      for (int r = 0; r < 4; ++r) {
        float rst = (mem[nt][r] > THR) ? 1.f : 0.f;
        mem[nt][r] = BETA * mem[nt][r] + (acc[r] + sh[nt]) - rst;
        packed |= (mem[nt][r] > THR ? 1u : 0u) << (8 * r);
      }
      st[nt] = packed;
    }
    if (dostore) {
      uint32_t idx0 = (uint32_t)(t * 64 + item) * (KTOT / 4) + r16 * (L2PAD / 4) + (pos_base >> 2);
      spk2[idx0] = st[0];
      spk2[idx0 + 16 * (L2PAD / 4)] = st[1];
    }
  }
}

// ---------------- K5: fc1 MFMA GEMM, LDS-free, 2-deep register double-buffer pipeline ----------------
// grid (KSPLIT, 50), 256 thr = 4 waves; wave wv owns N-cols [wv*64, wv*64+64)
#define LD_A(A_, CH_) { \
  _Pragma("unroll") for (int mi = 0; mi < 4; ++mi) \
    A_[mi] = *reinterpret_cast<const uint2*>(abase + (size_t)mi * 16 * KTOT + (size_t)(CH_) * 32); }
#define LD_B(B_, CH_) { \
  _Pragma("unroll") for (int ni = 0; ni < 4; ++ni) { \
    B_[2 * ni]     = *reinterpret_cast<const bf16x8*>(bbase + (size_t)(CH_) * 32768 + ni * 2048); \
    B_[2 * ni + 1] = *reinterpret_cast<const bf16x8*>(bbase + (size_t)(CH_) * 32768 + ni * 2048 + 1024); } }
#define FMA_STEP(A_, B_) { \
  bf16x8 af[4]; \
  _Pragma("unroll") for (int mi = 0; mi < 4; ++mi) af[mi] = frag_from_bytes(A_[mi]); \
  _Pragma("unroll") for (int ni = 0; ni < 4; ++ni) \
    _Pragma("unroll") for (int mi = 0; mi < 4; ++mi) { \
      acc[mi][ni] = __builtin_amdgcn_mfma_f32_16x16x32_bf16(af[mi], B_[2 * ni], acc[mi][ni], 0, 0, 0); \
      acc[mi][ni] = __builtin_amdgcn_mfma_f32_16x16x32_bf16(af[mi], B_[2 * ni + 1], acc[mi][ni], 0, 0, 0); } }

__global__ __launch_bounds__(256) void k_fc1(const uint8_t* __restrict__ spk2,
                                             const uint8_t* __restrict__ wTf,
                                             float* __restrict__ part) {
  int ks = blockIdx.x;
  int m0 = blockIdx.y * 64;
  int tid = threadIdx.x;
  int lane = tid & 63, wv = tid >> 6;
  int r16 = lane & 15, kg = lane >> 4;

  f32x4 acc[4][4];
#pragma unroll
  for (int mi = 0; mi < 4; ++mi)
#pragma unroll
    for (int ni = 0; ni < 4; ++ni) acc[mi][ni] = (f32x4){0.f, 0.f, 0.f, 0.f};

  const uint8_t* abase = spk2 + (size_t)(m0 + r16) * KTOT + ks * KRANGE + kg * 8;
  const uint8_t* bbase = wTf + (size_t)ks * KSTEPS * 32768 + wv * 8192 + lane * 16;

  uint2 a0[4], a1[4];
  bf16x8 b0[8], b1[8];

  LD_A(a0, 0); LD_B(b0, 0);
  for (int ch = 0; ch < KSTEPS; ch += 2) {
    LD_A(a1, ch + 1); LD_B(b1, ch + 1);          // KSTEPS even -> ch+1 always valid
    FMA_STEP(a0, b0);
    if (ch + 2 < KSTEPS) { LD_A(a0, ch + 2); LD_B(b0, ch + 2); }
    FMA_STEP(a1, b1);
  }

  int colb = wv * 64 + r16;
  int rowb = m0 + kg * 4;
#pragma unroll
  for (int mi = 0; mi < 4; ++mi)
#pragma unroll
    for (int ni = 0; ni < 4; ++ni) {
      float* pp = part + (size_t)(ks * MROWS + rowb + mi * 16) * NPAD + colb + ni * 16;
#pragma unroll
      for (int r = 0; r < 4; ++r) pp[r * NPAD] = acc[mi][ni][r];
    }
}

// ---------------- K6: reduce K-splits + fc1 bias + LIF3 + rate/latency -> comb [64][500] ----------------
__global__ __launch_bounds__(256) void k_lif3(const float* __restrict__ part,
                                              const float* __restrict__ fc1b,
                                              float* __restrict__ comb) {
  int item = blockIdx.x;
  int n = threadIdx.x;
  if (n >= NFC) return;
  float mem = 0.f, cnt = 0.f;
  int first = -1;
  float bias = fc1b[n];
  for (int t = 0; t < T_STEPS; ++t) {
    int row = t * NITEM + item;
    float s = bias;
#pragma unroll
    for (int ksx = 0; ksx < KSPLIT; ++ksx) s += part[(ksx * MROWS + row) * NPAD + n];
    float r = (mem > THR) ? 1.f : 0.f;
    mem = BETA * mem + s - r;
    if (mem > THR) { cnt += 1.f; if (first < 0) first = t; }
  }
  comb[item * 500 + n] = cnt;
  comb[item * 500 + NFC + n] = (first < 0) ? 0.f : ((float)first / (float)T_STEPS);
}

// ---------------- K7: head GEMM [64]x[500]->[128] + L2 normalize -> d_out ----------------
__global__ __launch_bounds__(128) void k_head(const float* __restrict__ comb,
                                              const float* __restrict__ fcsw,
                                              const float* __restrict__ fcsb,
                                              float* __restrict__ dout) {
  __shared__ float cr[500];
  __shared__ float red[2];
  int item = blockIdx.x;
  int o = threadIdx.x;
  for (int i = o; i < 500; i += 128) cr[i] = comb[item * 500 + i];
  __syncthreads();
  float acc = fcsb[o];
  for (int j = 0; j < 500; ++j) acc += cr[j] * fcsw[o * 500 + j];
  float sq = acc * acc;
  for (int off = 32; off > 0; off >>= 1) sq += __shfl_down(sq, off, 64);
  if ((o & 63) == 0) red[o >> 6] = sq;
  __syncthreads();
  float norm = sqrtf(red[0] + red[1]);
  norm = fmaxf(norm, 1e-12f);
  dout[item * 128 + o] = acc / norm;
}

// ---------------- launch ----------------
extern "C" void kernel_launch(void* const* d_in, const int* in_sizes, int n_in,
                              void* d_out, int out_size, void* d_ws, size_t ws_size,
                              hipStream_t stream) {
  const float* x1   = (const float*)d_in[0];
  const float* x2   = (const float*)d_in[1];
  const float* c1w  = (const float*)d_in[2];
  const float* c1b  = (const float*)d_in[3];
  const float* bn1g = (const float*)d_in[4];
  const float* bn1b = (const float*)d_in[5];
  const float* bn1m = (const float*)d_in[6];
  const float* bn1v = (const float*)d_in[7];
  const float* c2w  = (const float*)d_in[8];
  const float* c2b  = (const float*)d_in[9];
  const float* bn2g = (const float*)d_in[10];
  const float* bn2b = (const float*)d_in[11];
  const float* bn2m = (const float*)d_in[12];
  const float* bn2v = (const float*)d_in[13];
  const float* fc1w = (const float*)d_in[14];
  const float* fc1b = (const float*)d_in[15];
  const float* fcsw = (const float*)d_in[16];
  const float* fcsb = (const float*)d_in[17];

  char* ws = (char*)d_ws;
  float*    cur1    = (float*)(ws + OFF_CUR1);
  uint8_t*  wfrag   = (uint8_t*)(ws + OFF_CUR1);   // reused AFTER k_lif1
  uint8_t*  pooledT = (uint8_t*)(ws + OFF_POOL);
  uint8_t*  spk2    = (uint8_t*)(ws + OFF_SPK2);
  uint8_t*  wTf     = (uint8_t*)(ws + OFF_WT);
  float*    part    = (float*)(ws + OFF_PART);
  float*    comb    = (float*)(ws + OFF_COMB);

  k_wt<<<dim3(NKTILE), dim3(256), 0, stream>>>(fc1w, wTf);
  k_conv1<<<dim3(8, NITEM), dim3(256), 0, stream>>>(x1, x2, c1w, c1b, bn1g, bn1b, bn1m, bn1v, cur1);
  k_lif1<<<dim3(8, NITEM), dim3(256), 0, stream>>>(cur1, pooledT);
  k_wc2<<<dim3(1), dim3(512), 0, stream>>>(c2w, c2b, bn2g, bn2b, bn2m, bn2v, wfrag);
  k_conv2<<<dim3(8, NITEM), dim3(256), 0, stream>>>(pooledT, wfrag, (uint32_t*)spk2);
  k_fc1<<<dim3(KSPLIT, MROWS / 64), dim3(256), 0, stream>>>(spk2, wTf, part);
  k_lif3<<<dim3(NITEM), dim3(256), 0, stream>>>(part, fc1b, comb);
  k_head<<<dim3(NITEM), dim3(128), 0, stream>>>(comb, fcsw, fcsb, (float*)d_out);
}

// Round 6
// 245.384 us; speedup vs baseline: 1.0028x; 1.0028x over previous
//
#include <hip/hip_runtime.h>
#include <math.h>
#include <stdint.h>

// ---------------- dims ----------------
#define BETA 0.9f
#define THR 1.0f
#define T_STEPS 50
#define BN_EPS 1e-5f

#define NITEM 64          // 2 inputs x 32 batch
#define C1 16
#define L1 1981           // conv1 out length
#define L1P 1984          // padded
#define P4 495            // pooled length
#define C2 32
#define L2 493            // conv2 out length
#define L2PAD 496
#define KTOT 15872        // C2*L2PAD (padded flat dim)
#define KREAL 15776       // C2*L2
#define NFC 250
#define NPAD 256
#define KSPLIT 8
#define KRANGE 1984       // KTOT/KSPLIT
#define KSTEPS 62         // KRANGE/32
#define NKTILE 496        // KTOT/32
#define MROWS 3200        // T_STEPS*NITEM

// ---------------- workspace layout (bytes) ----------------
#define OFF_CUR1 0UL
#define OFF_POOL 8126464UL            // 64*16*1984*4
#define OFF_SPK2 34340864UL           // + 26214400
#define OFF_WT   85131264UL           // + 50*64*15872
#define OFF_PART 101384192UL          // + 496*32768 (wTf = 16252928 B)
#define OFF_COMB 127598592UL          // + 8*3200*256*4
// cur1 region (8.1 MB) reuse after k_lif1: wfrag at +0 (8.5 KB), cur3 at +16384 (3.27 MB)
#define OFF_CUR3 16384UL

typedef __attribute__((ext_vector_type(8))) short bf16x8;
typedef __attribute__((ext_vector_type(4))) float f32x4;

__device__ __forceinline__ uint32_t f32_to_bf16_rne(float f) {
  uint32_t u = __float_as_uint(f);
  return (u + 0x7FFFu + ((u >> 16) & 1u)) >> 16;
}

__device__ __forceinline__ void gload_lds16(const void* g, void* l) {
  __builtin_amdgcn_global_load_lds(
      (const __attribute__((address_space(1))) uint32_t*)g,
      (__attribute__((address_space(3))) uint32_t*)l, 16, 0, 0);
}

// spike bytes (bit0) -> 8 bf16 {0,1}
__device__ __forceinline__ bf16x8 frag_from_bytes(uint2 a) {
  union { uint32_t u[4]; bf16x8 v; } c;
  c.u[0] = (a.x & 1u) * 0x3F80u | ((a.x >> 8) & 1u) * 0x3F800000u;
  c.u[1] = ((a.x >> 16) & 1u) * 0x3F80u | ((a.x >> 24) & 1u) * 0x3F800000u;
  c.u[2] = (a.y & 1u) * 0x3F80u | ((a.y >> 8) & 1u) * 0x3F800000u;
  c.u[3] = ((a.y >> 16) & 1u) * 0x3F80u | ((a.y >> 24) & 1u) * 0x3F800000u;
  return c.v;
}

// ---------------- K1: fc1w [250,15776] -> wTf wave-fragment-ready bf16 hi/lo ----------------
// per k-tile (32 k's): [wv(4)][ni(4)][sel(2)][lane(64)][16B] = 32 KB
__global__ __launch_bounds__(256) void k_wt(const float* __restrict__ fc1w,
                                            uint8_t* __restrict__ wTf) {
  int kt = blockIdx.x;        // 0..495
  int n = threadIdx.x;        // 0..255
  int wv = n >> 6, ni = (n >> 4) & 3, r16 = n & 15;
  uint32_t hibuf[16], lobuf[16];
#pragma unroll 4
  for (int p = 0; p < 16; ++p) {
    uint32_t h2 = 0, l2 = 0;
#pragma unroll
    for (int e = 0; e < 2; ++e) {
      int k = kt * 32 + p * 2 + e;
      int oc = k / L2PAD;
      int pos = k - oc * L2PAD;
      float w = 0.f;
      if (pos < L2 && n < NFC) w = fc1w[n * KREAL + oc * L2 + pos];
      uint32_t hb = f32_to_bf16_rne(w);
      float hf = __uint_as_float(hb << 16);
      uint32_t lb = f32_to_bf16_rne(w - hf);
      h2 |= hb << (16 * e);
      l2 |= lb << (16 * e);
    }
    hibuf[p] = h2;
    lobuf[p] = l2;
  }
  uint8_t* tb = wTf + (size_t)kt * 32768 + wv * 8192 + ni * 2048;
#pragma unroll
  for (int kgi = 0; kgi < 4; ++kgi) {
    uint4 h; h.x = hibuf[4 * kgi]; h.y = hibuf[4 * kgi + 1]; h.z = hibuf[4 * kgi + 2]; h.w = hibuf[4 * kgi + 3];
    *reinterpret_cast<uint4*>(tb + (kgi * 16 + r16) * 16) = h;
    uint4 l; l.x = lobuf[4 * kgi]; l.y = lobuf[4 * kgi + 1]; l.z = lobuf[4 * kgi + 2]; l.w = lobuf[4 * kgi + 3];
    *reinterpret_cast<uint4*>(tb + 1024 + (kgi * 16 + r16) * 16) = l;
  }
}

// ---------------- K2: conv1 (K=80, stride4) + BN1 fold -> cur1 [64][16][1984] ----------------
// float4 LDS reads: 16B/lane -> every 8 lanes cover all 32 banks (bank-optimal)
__global__ __launch_bounds__(256) void k_conv1(const float* __restrict__ x1, const float* __restrict__ x2,
                                               const float* __restrict__ c1w, const float* __restrict__ c1b,
                                               const float* __restrict__ g, const float* __restrict__ bb,
                                               const float* __restrict__ mn, const float* __restrict__ vr,
                                               float* __restrict__ cur1) {
  __shared__ __align__(16) float xs[1104];
  int item = blockIdx.y;
  int pc = blockIdx.x;                 // 0..7
  int tid = threadIdx.x;
  const float* x = (item < 32 ? x1 : x2) + (item & 31) * 8000;
  int xoff = pc * 1024;
  for (int i = tid; i < 1100; i += 256) {
    int gi = xoff + i;
    xs[i] = (gi < 8000) ? x[gi] : 0.f;
  }
  __syncthreads();
  int p = pc * 256 + tid;
  bool pv = (p < L1);
  const float4* xs4 = reinterpret_cast<const float4*>(xs);
  for (int c = 0; c < C1; ++c) {
    float s = g[c] / sqrtf(vr[c] + BN_EPS);
    float sh = (c1b[c] - mn[c]) * s + bb[c];
    const float4* w4 = reinterpret_cast<const float4*>(c1w + c * 80);
    float acc = 0.f;
#pragma unroll
    for (int k4 = 0; k4 < 20; ++k4) {
      float4 wv4 = w4[k4];
      float4 xv = xs4[tid + k4];
      acc += wv4.x * xv.x; acc += wv4.y * xv.y;
      acc += wv4.z * xv.z; acc += wv4.w * xv.w;
    }
    if (pv) cur1[(item * C1 + c) * L1P + p] = acc * s + sh;
  }
}

// ---------------- K3: LIF1 + maxpool4, coalesced u32 stores -> pooled_T [item][t][512][16] ----------------
__global__ __launch_bounds__(256) void k_lif1(const float* __restrict__ cur1,
                                              uint8_t* __restrict__ pooledT) {
  int item = blockIdx.y;
  int g = threadIdx.x & 3;
  int p4 = blockIdx.x * 64 + (threadIdx.x >> 2);
  if (p4 >= P4) return;
  float4 cv[4];
#pragma unroll
  for (int j = 0; j < 4; ++j)
    cv[j] = *reinterpret_cast<const float4*>(cur1 + ((size_t)item * C1 + g * 4 + j) * L1P + 4 * p4);
  float m[4][4];
#pragma unroll
  for (int j = 0; j < 4; ++j)
#pragma unroll
    for (int r = 0; r < 4; ++r) m[j][r] = 0.f;
  uint32_t* out = reinterpret_cast<uint32_t*>(pooledT + ((size_t)item * 50 * 512 + p4) * 16 + g * 4);
  for (int t = 0; t < T_STEPS; ++t) {
    uint32_t pk = 0;
#pragma unroll
    for (int j = 0; j < 4; ++j) {
      int s = 0;
#pragma unroll
      for (int r = 0; r < 4; ++r) {
        float rst = (m[j][r] > THR) ? 1.f : 0.f;
        float cvv = (r == 0) ? cv[j].x : (r == 1) ? cv[j].y : (r == 2) ? cv[j].z : cv[j].w;
        m[j][r] = BETA * m[j][r] + cvv - rst;
        s |= (m[j][r] > THR);
      }
      pk |= ((uint32_t)s) << (8 * j);
    }
    out[t * 2048] = pk;
  }
}

// ---------------- K3b: conv2 weight frags (hi/lo, BN-folded) + sh2 -> wfrag (cur1 region) ----------------
__global__ __launch_bounds__(512) void k_wc2(const float* __restrict__ c2w, const float* __restrict__ c2b,
                                             const float* __restrict__ g, const float* __restrict__ bb,
                                             const float* __restrict__ mn, const float* __restrict__ vr,
                                             uint8_t* __restrict__ wfrag) {
  int t = threadIdx.x;
  int lane = t & 63;
  int fr = t >> 6;
  int hl = fr & 1, kt = (fr >> 1) & 1, nt = fr >> 2;
  int n16 = lane & 15, kg = lane >> 4;
  int oc = nt * 16 + n16;
  float s2 = g[oc] * rsqrtf(vr[oc] + BN_EPS);
  uint32_t w[4];
#pragma unroll
  for (int i = 0; i < 4; ++i) {
    uint32_t packed = 0;
#pragma unroll
    for (int e = 0; e < 2; ++e) {
      int j = i * 2 + e;
      int k = kt * 32 + kg * 8 + j;
      int tap = k >> 4, ic = k & 15;
      float raw = (tap < 3) ? c2w[oc * 48 + ic * 3 + tap] * s2 : 0.f;
      uint32_t hb = f32_to_bf16_rne(raw);
      float hf = __uint_as_float(hb << 16);
      uint32_t lb = f32_to_bf16_rne(raw - hf);
      uint32_t v = hl ? lb : hb;
      packed |= v << (16 * e);
    }
    w[i] = packed;
  }
  uint4 uu; uu.x = w[0]; uu.y = w[1]; uu.z = w[2]; uu.w = w[3];
  *reinterpret_cast<uint4*>(wfrag + fr * 1024 + lane * 16) = uu;
  if (t < C2) {
    float s2b = g[t] * rsqrtf(vr[t] + BN_EPS);
    reinterpret_cast<float*>(wfrag + 8192)[t] = (c2b[t] - mn[t]) * s2b + bb[t];
  }
}

// ---------------- K4: conv2 via MFMA + LIF2 (mem in acc lanes) -> spk2 bytes ----------------
__global__ __launch_bounds__(256) void k_conv2(const uint8_t* __restrict__ pooledT,
                                               const uint8_t* __restrict__ wfrag,
                                               uint32_t* __restrict__ spk2) {
  int item = blockIdx.y;
  int pt = blockIdx.x;
  int tid = threadIdx.x;
  int lane = tid & 63, wv = tid >> 6;
  int r16 = lane & 15, kg = lane >> 4;
  bf16x8 bw[2][2][2];
#pragma unroll
  for (int nt = 0; nt < 2; ++nt)
#pragma unroll
    for (int kt = 0; kt < 2; ++kt)
#pragma unroll
      for (int hl = 0; hl < 2; ++hl)
        bw[nt][kt][hl] = *reinterpret_cast<const bf16x8*>(wfrag + (nt * 4 + kt * 2 + hl) * 1024 + lane * 16);
  float sh[2];
  sh[0] = reinterpret_cast<const float*>(wfrag + 8192)[r16];
  sh[1] = reinterpret_cast<const float*>(wfrag + 8192)[16 + r16];
  const uint8_t* base = pooledT + (size_t)item * 50 * 8192;
  int rowA = pt * 64 + wv * 16 + r16;
  size_t off0 = (size_t)(rowA + (kg >> 1)) * 16 + 8 * (kg & 1);   // taps 0/1
  size_t off1 = (size_t)(rowA + 2) * 16 + 8 * (kg & 1);           // tap 2 (+pad)
  uint2 na0 = *reinterpret_cast<const uint2*>(base + off0);
  uint2 na1 = *reinterpret_cast<const uint2*>(base + off1);
  float mem[2][4] = {{0.f, 0.f, 0.f, 0.f}, {0.f, 0.f, 0.f, 0.f}};
  int pos_base = pt * 64 + wv * 16 + kg * 4;
  bool dostore = pos_base < L2PAD;
  for (int t = 0; t < T_STEPS; ++t) {
    uint2 a0 = na0, a1 = na1;
    const uint8_t* nb = base + (size_t)((t + 1 < T_STEPS) ? t + 1 : t) * 8192;
    na0 = *reinterpret_cast<const uint2*>(nb + off0);
    na1 = *reinterpret_cast<const uint2*>(nb + off1);
    bf16x8 af0 = frag_from_bytes(a0);
    bf16x8 af1 = frag_from_bytes(a1);
    uint32_t st[2];
#pragma unroll
    for (int nt = 0; nt < 2; ++nt) {
      f32x4 acc = (f32x4){0.f, 0.f, 0.f, 0.f};
      acc = __builtin_amdgcn_mfma_f32_16x16x32_bf16(af0, bw[nt][0][0], acc, 0, 0, 0);
      acc = __builtin_amdgcn_mfma_f32_16x16x32_bf16(af1, bw[nt][1][0], acc, 0, 0, 0);
      acc = __builtin_amdgcn_mfma_f32_16x16x32_bf16(af0, bw[nt][0][1], acc, 0, 0, 0);
      acc = __builtin_amdgcn_mfma_f32_16x16x32_bf16(af1, bw[nt][1][1], acc, 0, 0, 0);
      uint32_t packed = 0;
#pragma unroll
      for (int r = 0; r < 4; ++r) {
        float rst = (mem[nt][r] > THR) ? 1.f : 0.f;
        mem[nt][r] = BETA * mem[nt][r] + (acc[r] + sh[nt]) - rst;
        packed |= (mem[nt][r] > THR ? 1u : 0u) << (8 * r);
      }
      st[nt] = packed;
    }
    if (dostore) {
      uint32_t idx0 = (uint32_t)(t * 64 + item) * (KTOT / 4) + r16 * (L2PAD / 4) + (pos_base >> 2);
      spk2[idx0] = st[0];
      spk2[idx0 + 16 * (L2PAD / 4)] = st[1];
    }
  }
}

// ---------------- K5: fc1 MFMA GEMM, 2-phase LDS double-buffer (T3-minimum recipe) ----------------
// grid (KSPLIT, 50), 256 thr = 4 waves; wave wv owns N-cols [wv*64, wv*64+64)
// B staged via global_load_lds into fragment-ready layout (ds_read_b128 lane-contiguous, conflict-free)
#define LD_A(A_, CH_) { \
  _Pragma("unroll") for (int mi = 0; mi < 4; ++mi) \
    A_[mi] = *reinterpret_cast<const uint2*>(abase + (size_t)mi * 16 * KTOT + (size_t)(CH_) * 32); }
#define STAGE_B(BUF_, CH_) { \
  const uint8_t* s_ = bsrc0 + (size_t)(CH_) * 32768; \
  _Pragma("unroll") for (int i_ = 0; i_ < 8; ++i_) { \
    int idx_ = i_ * 256 + tid; \
    gload_lds16(s_ + idx_ * 16, &Bl[BUF_][idx_ * 16]); } }
#define FMA_LDS(BUF_, A_) { \
  bf16x8 af[4]; \
  _Pragma("unroll") for (int mi = 0; mi < 4; ++mi) af[mi] = frag_from_bytes(A_[mi]); \
  _Pragma("unroll") for (int ni = 0; ni < 4; ++ni) { \
    bf16x8 bh = *reinterpret_cast<const bf16x8*>(&Bl[BUF_][wv * 8192 + ni * 2048 + lane * 16]); \
    bf16x8 bl = *reinterpret_cast<const bf16x8*>(&Bl[BUF_][wv * 8192 + ni * 2048 + 1024 + lane * 16]); \
    _Pragma("unroll") for (int mi = 0; mi < 4; ++mi) { \
      acc[mi][ni] = __builtin_amdgcn_mfma_f32_16x16x32_bf16(af[mi], bh, acc[mi][ni], 0, 0, 0); \
      acc[mi][ni] = __builtin_amdgcn_mfma_f32_16x16x32_bf16(af[mi], bl, acc[mi][ni], 0, 0, 0); } } }

__global__ __launch_bounds__(256) void k_fc1(const uint8_t* __restrict__ spk2,
                                             const uint8_t* __restrict__ wTf,
                                             float* __restrict__ part) {
  __shared__ __align__(16) uint8_t Bl[2][32768];
  int ks = blockIdx.x;
  int m0 = blockIdx.y * 64;
  int tid = threadIdx.x;
  int lane = tid & 63, wv = tid >> 6;
  int r16 = lane & 15, kg = lane >> 4;

  f32x4 acc[4][4];
#pragma unroll
  for (int mi = 0; mi < 4; ++mi)
#pragma unroll
    for (int ni = 0; ni < 4; ++ni) acc[mi][ni] = (f32x4){0.f, 0.f, 0.f, 0.f};

  const uint8_t* abase = spk2 + (size_t)(m0 + r16) * KTOT + ks * KRANGE + kg * 8;
  const uint8_t* bsrc0 = wTf + (size_t)ks * KSTEPS * 32768;

  uint2 a0[4], a1[4];

  // prologue: stage tile 0, load A0, drain, sync
  STAGE_B(0, 0);
  LD_A(a0, 0);
  asm volatile("s_waitcnt vmcnt(0)" ::: "memory");
  __builtin_amdgcn_s_barrier();

  for (int ch = 0; ch < KSTEPS; ch += 2) {
    // even tile: prefetch tile ch+1 (always exists, KSTEPS even), compute buf0
    STAGE_B(1, ch + 1);
    LD_A(a1, ch + 1);
    FMA_LDS(0, a0);
    asm volatile("s_waitcnt vmcnt(0)" ::: "memory");
    __builtin_amdgcn_sched_barrier(0);
    __builtin_amdgcn_s_barrier();
    // odd tile: prefetch tile ch+2 (if any), compute buf1
    if (ch + 2 < KSTEPS) {
      STAGE_B(0, ch + 2);
      LD_A(a0, ch + 2);
    }
    FMA_LDS(1, a1);
    if (ch + 2 < KSTEPS) {
      asm volatile("s_waitcnt vmcnt(0)" ::: "memory");
      __builtin_amdgcn_sched_barrier(0);
      __builtin_amdgcn_s_barrier();
    }
  }

  int colb = wv * 64 + r16;
  int rowb = m0 + kg * 4;
#pragma unroll
  for (int mi = 0; mi < 4; ++mi)
#pragma unroll
    for (int ni = 0; ni < 4; ++ni) {
      float* pp = part + (size_t)(ks * MROWS + rowb + mi * 16) * NPAD + colb + ni * 16;
#pragma unroll
      for (int r = 0; r < 4; ++r) pp[r * NPAD] = acc[mi][ni][r];
    }
}

// ---------------- K6a: reduce K-splits: cur3[3200][256] = sum_ks part[ks][.][.] ----------------
__global__ __launch_bounds__(256) void k_red(const float* __restrict__ part,
                                             float* __restrict__ cur3) {
  int i = blockIdx.x * 256 + threadIdx.x;
  float s = 0.f;
#pragma unroll
  for (int ksx = 0; ksx < KSPLIT; ++ksx) s += part[(size_t)ksx * MROWS * NPAD + i];
  cur3[i] = s;
}

// ---------------- K6b: fc1 bias + LIF3 + rate/latency -> comb [64][500] ----------------
__global__ __launch_bounds__(256) void k_lif3(const float* __restrict__ cur3,
                                              const float* __restrict__ fc1b,
                                              float* __restrict__ comb) {
  int item = blockIdx.x;
  int n = threadIdx.x;
  if (n >= NFC) return;
  float bias = fc1b[n];
  float sv[T_STEPS];
#pragma unroll
  for (int t = 0; t < T_STEPS; ++t)
    sv[t] = cur3[(size_t)(t * NITEM + item) * NPAD + n];
  float mem = 0.f, cnt = 0.f;
  int first = -1;
#pragma unroll
  for (int t = 0; t < T_STEPS; ++t) {
    float r = (mem > THR) ? 1.f : 0.f;
    mem = BETA * mem + (bias + sv[t]) - r;
    if (mem > THR) { cnt += 1.f; if (first < 0) first = t; }
  }
  comb[item * 500 + n] = cnt;
  comb[item * 500 + NFC + n] = (first < 0) ? 0.f : ((float)first / (float)T_STEPS);
}

// ---------------- K7: head GEMM [64]x[500]->[128] + L2 normalize -> d_out ----------------
__global__ __launch_bounds__(128) void k_head(const float* __restrict__ comb,
                                              const float* __restrict__ fcsw,
                                              const float* __restrict__ fcsb,
                                              float* __restrict__ dout) {
  __shared__ float cr[500];
  __shared__ float red[2];
  int item = blockIdx.x;
  int o = threadIdx.x;
  for (int i = o; i < 500; i += 128) cr[i] = comb[item * 500 + i];
  __syncthreads();
  float acc = fcsb[o];
  for (int j = 0; j < 500; ++j) acc += cr[j] * fcsw[o * 500 + j];
  float sq = acc * acc;
  for (int off = 32; off > 0; off >>= 1) sq += __shfl_down(sq, off, 64);
  if ((o & 63) == 0) red[o >> 6] = sq;
  __syncthreads();
  float norm = sqrtf(red[0] + red[1]);
  norm = fmaxf(norm, 1e-12f);
  dout[item * 128 + o] = acc / norm;
}

// ---------------- launch ----------------
extern "C" void kernel_launch(void* const* d_in, const int* in_sizes, int n_in,
                              void* d_out, int out_size, void* d_ws, size_t ws_size,
                              hipStream_t stream) {
  const float* x1   = (const float*)d_in[0];
  const float* x2   = (const float*)d_in[1];
  const float* c1w  = (const float*)d_in[2];
  const float* c1b  = (const float*)d_in[3];
  const float* bn1g = (const float*)d_in[4];
  const float* bn1b = (const float*)d_in[5];
  const float* bn1m = (const float*)d_in[6];
  const float* bn1v = (const float*)d_in[7];
  const float* c2w  = (const float*)d_in[8];
  const float* c2b  = (const float*)d_in[9];
  const float* bn2g = (const float*)d_in[10];
  const float* bn2b = (const float*)d_in[11];
  const float* bn2m = (const float*)d_in[12];
  const float* bn2v = (const float*)d_in[13];
  const float* fc1w = (const float*)d_in[14];
  const float* fc1b = (const float*)d_in[15];
  const float* fcsw = (const float*)d_in[16];
  const float* fcsb = (const float*)d_in[17];

  char* ws = (char*)d_ws;
  float*    cur1    = (float*)(ws + OFF_CUR1);
  uint8_t*  wfrag   = (uint8_t*)(ws + OFF_CUR1);          // reused AFTER k_lif1
  float*    cur3    = (float*)(ws + OFF_CUR1 + OFF_CUR3); // reused AFTER k_lif1
  uint8_t*  pooledT = (uint8_t*)(ws + OFF_POOL);
  uint8_t*  spk2    = (uint8_t*)(ws + OFF_SPK2);
  uint8_t*  wTf     = (uint8_t*)(ws + OFF_WT);
  float*    part    = (float*)(ws + OFF_PART);
  float*    comb    = (float*)(ws + OFF_COMB);

  k_wt<<<dim3(NKTILE), dim3(256), 0, stream>>>(fc1w, wTf);
  k_conv1<<<dim3(8, NITEM), dim3(256), 0, stream>>>(x1, x2, c1w, c1b, bn1g, bn1b, bn1m, bn1v, cur1);
  k_lif1<<<dim3(8, NITEM), dim3(256), 0, stream>>>(cur1, pooledT);
  k_wc2<<<dim3(1), dim3(512), 0, stream>>>(c2w, c2b, bn2g, bn2b, bn2m, bn2v, wfrag);
  k_conv2<<<dim3(8, NITEM), dim3(256), 0, stream>>>(pooledT, wfrag, (uint32_t*)spk2);
  k_fc1<<<dim3(KSPLIT, MROWS / 64), dim3(256), 0, stream>>>(spk2, wTf, part);
  k_red<<<dim3(MROWS * NPAD / 256), dim3(256), 0, stream>>>(part, cur3);
  k_lif3<<<dim3(NITEM), dim3(256), 0, stream>>>(cur3, fc1b, comb);
  k_head<<<dim3(NITEM), dim3(128), 0, stream>>>(comb, fcsw, fcsb, (float*)d_out);
}

// Round 7
// 219.536 us; speedup vs baseline: 1.1209x; 1.1177x over previous
//
#include <hip/hip_runtime.h>
#include <math.h>
#include <stdint.h>

// ---------------- dims ----------------
#define BETA 0.9f
#define THR 1.0f
#define T_STEPS 50
#define BN_EPS 1e-5f

#define NITEM 64          // 2 inputs x 32 batch
#define C1 16
#define L1 1981           // conv1 out length
#define L1P 1984          // padded
#define P4 495            // pooled length
#define C2 32
#define L2 493            // conv2 out length
#define L2PAD 496
#define KTOT 15872        // C2*L2PAD (padded flat dim)
#define KREAL 15776       // C2*L2
#define NFC 250
#define NPAD 256
#define KSPLIT 16
#define KRANGE 992        // KTOT/KSPLIT
#define KSTEPS 31         // KRANGE/32
#define NKTILE 496        // KTOT/32
#define MROWS 3200        // T_STEPS*NITEM
#define TSLICE 1015808    // KTOT*64 bytes per t (blocked spk2 slice)

// ---------------- workspace layout (bytes) ----------------
#define OFF_CUR1 0UL
#define OFF_POOL 8126464UL            // 64*16*1984*4
#define OFF_SPK2 34340864UL           // + 26214400 (pooledT; REUSED as part slices 8..15 after conv2)
#define OFF_WT   85131264UL           // + 50790400 (spk2 blocked = 50*TSLICE)
#define OFF_PART 101384192UL          // + 16252928 (wTf)
#define OFF_COMB 127598592UL          // + 8*3200*256*4 (part slices 0..7)
// cur1 region reuse after k_lif1: wfrag at +0 (8.5 KB), cur3 at +16384 (3.27 MB)
#define OFF_CUR3 16384UL

typedef __attribute__((ext_vector_type(8))) short bf16x8;
typedef __attribute__((ext_vector_type(4))) float f32x4;

__device__ __forceinline__ uint32_t f32_to_bf16_rne(float f) {
  uint32_t u = __float_as_uint(f);
  return (u + 0x7FFFu + ((u >> 16) & 1u)) >> 16;
}

// spike bytes (bit0) -> 8 bf16 {0,1}
__device__ __forceinline__ bf16x8 frag_from_bytes(uint2 a) {
  union { uint32_t u[4]; bf16x8 v; } c;
  c.u[0] = (a.x & 1u) * 0x3F80u | ((a.x >> 8) & 1u) * 0x3F800000u;
  c.u[1] = ((a.x >> 16) & 1u) * 0x3F80u | ((a.x >> 24) & 1u) * 0x3F800000u;
  c.u[2] = (a.y & 1u) * 0x3F80u | ((a.y >> 8) & 1u) * 0x3F800000u;
  c.u[3] = ((a.y >> 16) & 1u) * 0x3F80u | ((a.y >> 24) & 1u) * 0x3F800000u;
  return c.v;
}

// ---------------- K1: fc1w [250,15776] -> wTf wave-fragment-ready bf16 hi/lo ----------------
// per k-tile (32 k's): [wv(4)][ni(4)][sel(2)][lane(64)][16B] = 32 KB
__global__ __launch_bounds__(256) void k_wt(const float* __restrict__ fc1w,
                                            uint8_t* __restrict__ wTf) {
  int kt = blockIdx.x;        // 0..495
  int n = threadIdx.x;        // 0..255
  int wv = n >> 6, ni = (n >> 4) & 3, r16 = n & 15;
  uint32_t hibuf[16], lobuf[16];
#pragma unroll 4
  for (int p = 0; p < 16; ++p) {
    uint32_t h2 = 0, l2 = 0;
#pragma unroll
    for (int e = 0; e < 2; ++e) {
      int k = kt * 32 + p * 2 + e;
      int oc = k / L2PAD;
      int pos = k - oc * L2PAD;
      float w = 0.f;
      if (pos < L2 && n < NFC) w = fc1w[n * KREAL + oc * L2 + pos];
      uint32_t hb = f32_to_bf16_rne(w);
      float hf = __uint_as_float(hb << 16);
      uint32_t lb = f32_to_bf16_rne(w - hf);
      h2 |= hb << (16 * e);
      l2 |= lb << (16 * e);
    }
    hibuf[p] = h2;
    lobuf[p] = l2;
  }
  uint8_t* tb = wTf + (size_t)kt * 32768 + wv * 8192 + ni * 2048;
#pragma unroll
  for (int kgi = 0; kgi < 4; ++kgi) {
    uint4 h; h.x = hibuf[4 * kgi]; h.y = hibuf[4 * kgi + 1]; h.z = hibuf[4 * kgi + 2]; h.w = hibuf[4 * kgi + 3];
    *reinterpret_cast<uint4*>(tb + (kgi * 16 + r16) * 16) = h;
    uint4 l; l.x = lobuf[4 * kgi]; l.y = lobuf[4 * kgi + 1]; l.z = lobuf[4 * kgi + 2]; l.w = lobuf[4 * kgi + 3];
    *reinterpret_cast<uint4*>(tb + 1024 + (kgi * 16 + r16) * 16) = l;
  }
}

// ---------------- K2: conv1 (K=80, stride4) + BN1 fold -> cur1 [64][16][1984] ----------------
__global__ __launch_bounds__(256) void k_conv1(const float* __restrict__ x1, const float* __restrict__ x2,
                                               const float* __restrict__ c1w, const float* __restrict__ c1b,
                                               const float* __restrict__ g, const float* __restrict__ bb,
                                               const float* __restrict__ mn, const float* __restrict__ vr,
                                               float* __restrict__ cur1) {
  __shared__ __align__(16) float xs[1104];
  int item = blockIdx.y;
  int pc = blockIdx.x;                 // 0..7
  int tid = threadIdx.x;
  const float* x = (item < 32 ? x1 : x2) + (item & 31) * 8000;
  int xoff = pc * 1024;
  for (int i = tid; i < 1100; i += 256) {
    int gi = xoff + i;
    xs[i] = (gi < 8000) ? x[gi] : 0.f;
  }
  __syncthreads();
  int p = pc * 256 + tid;
  bool pv = (p < L1);
  const float4* xs4 = reinterpret_cast<const float4*>(xs);
  for (int c = 0; c < C1; ++c) {
    float s = g[c] / sqrtf(vr[c] + BN_EPS);
    float sh = (c1b[c] - mn[c]) * s + bb[c];
    const float4* w4 = reinterpret_cast<const float4*>(c1w + c * 80);
    float acc = 0.f;
#pragma unroll
    for (int k4 = 0; k4 < 20; ++k4) {
      float4 wv4 = w4[k4];
      float4 xv = xs4[tid + k4];
      acc += wv4.x * xv.x; acc += wv4.y * xv.y;
      acc += wv4.z * xv.z; acc += wv4.w * xv.w;
    }
    if (pv) cur1[(item * C1 + c) * L1P + p] = acc * s + sh;
  }
}

// ---------------- K3: LIF1 + maxpool4, coalesced u32 stores -> pooled_T [item][t][512][16] ----------------
__global__ __launch_bounds__(256) void k_lif1(const float* __restrict__ cur1,
                                              uint8_t* __restrict__ pooledT) {
  int item = blockIdx.y;
  int g = threadIdx.x & 3;
  int p4 = blockIdx.x * 64 + (threadIdx.x >> 2);
  if (p4 >= P4) return;
  float4 cv[4];
#pragma unroll
  for (int j = 0; j < 4; ++j)
    cv[j] = *reinterpret_cast<const float4*>(cur1 + ((size_t)item * C1 + g * 4 + j) * L1P + 4 * p4);
  float m[4][4];
#pragma unroll
  for (int j = 0; j < 4; ++j)
#pragma unroll
    for (int r = 0; r < 4; ++r) m[j][r] = 0.f;
  uint32_t* out = reinterpret_cast<uint32_t*>(pooledT + ((size_t)item * 50 * 512 + p4) * 16 + g * 4);
  for (int t = 0; t < T_STEPS; ++t) {
    uint32_t pk = 0;
#pragma unroll
    for (int j = 0; j < 4; ++j) {
      int s = 0;
#pragma unroll
      for (int r = 0; r < 4; ++r) {
        float rst = (m[j][r] > THR) ? 1.f : 0.f;
        float cvv = (r == 0) ? cv[j].x : (r == 1) ? cv[j].y : (r == 2) ? cv[j].z : cv[j].w;
        m[j][r] = BETA * m[j][r] + cvv - rst;
        s |= (m[j][r] > THR);
      }
      pk |= ((uint32_t)s) << (8 * j);
    }
    out[t * 2048] = pk;
  }
}

// ---------------- K3b: conv2 weight frags (hi/lo, BN-folded) + sh2 -> wfrag (cur1 region) ----------------
__global__ __launch_bounds__(512) void k_wc2(const float* __restrict__ c2w, const float* __restrict__ c2b,
                                             const float* __restrict__ g, const float* __restrict__ bb,
                                             const float* __restrict__ mn, const float* __restrict__ vr,
                                             uint8_t* __restrict__ wfrag) {
  int t = threadIdx.x;
  int lane = t & 63;
  int fr = t >> 6;
  int hl = fr & 1, kt = (fr >> 1) & 1, nt = fr >> 2;
  int n16 = lane & 15, kg = lane >> 4;
  int oc = nt * 16 + n16;
  float s2 = g[oc] * rsqrtf(vr[oc] + BN_EPS);
  uint32_t w[4];
#pragma unroll
  for (int i = 0; i < 4; ++i) {
    uint32_t packed = 0;
#pragma unroll
    for (int e = 0; e < 2; ++e) {
      int j = i * 2 + e;
      int k = kt * 32 + kg * 8 + j;
      int tap = k >> 4, ic = k & 15;
      float raw = (tap < 3) ? c2w[oc * 48 + ic * 3 + tap] * s2 : 0.f;
      uint32_t hb = f32_to_bf16_rne(raw);
      float hf = __uint_as_float(hb << 16);
      uint32_t lb = f32_to_bf16_rne(raw - hf);
      uint32_t v = hl ? lb : hb;
      packed |= v << (16 * e);
    }
    w[i] = packed;
  }
  uint4 uu; uu.x = w[0]; uu.y = w[1]; uu.z = w[2]; uu.w = w[3];
  *reinterpret_cast<uint4*>(wfrag + fr * 1024 + lane * 16) = uu;
  if (t < C2) {
    float s2b = g[t] * rsqrtf(vr[t] + BN_EPS);
    reinterpret_cast<float*>(wfrag + 8192)[t] = (c2b[t] - mn[t]) * s2b + bb[t];
  }
}

// ---------------- K4: conv2 via MFMA + LIF2 -> spk2 BLOCKED [t][kchunk][item][32B] ----------------
__global__ __launch_bounds__(256) void k_conv2(const uint8_t* __restrict__ pooledT,
                                               const uint8_t* __restrict__ wfrag,
                                               uint32_t* __restrict__ spk2) {
  int item = blockIdx.y;
  int pt = blockIdx.x;
  int tid = threadIdx.x;
  int lane = tid & 63, wv = tid >> 6;
  int r16 = lane & 15, kg = lane >> 4;
  bf16x8 bw[2][2][2];
#pragma unroll
  for (int nt = 0; nt < 2; ++nt)
#pragma unroll
    for (int kt = 0; kt < 2; ++kt)
#pragma unroll
      for (int hl = 0; hl < 2; ++hl)
        bw[nt][kt][hl] = *reinterpret_cast<const bf16x8*>(wfrag + (nt * 4 + kt * 2 + hl) * 1024 + lane * 16);
  float sh[2];
  sh[0] = reinterpret_cast<const float*>(wfrag + 8192)[r16];
  sh[1] = reinterpret_cast<const float*>(wfrag + 8192)[16 + r16];
  const uint8_t* base = pooledT + (size_t)item * 50 * 8192;
  int rowA = pt * 64 + wv * 16 + r16;
  size_t off0 = (size_t)(rowA + (kg >> 1)) * 16 + 8 * (kg & 1);   // taps 0/1
  size_t off1 = (size_t)(rowA + 2) * 16 + 8 * (kg & 1);           // tap 2 (+pad)
  uint2 na0 = *reinterpret_cast<const uint2*>(base + off0);
  uint2 na1 = *reinterpret_cast<const uint2*>(base + off1);
  float mem[2][4] = {{0.f, 0.f, 0.f, 0.f}, {0.f, 0.f, 0.f, 0.f}};
  int pos_base = pt * 64 + wv * 16 + kg * 4;
  bool dostore = pos_base < L2PAD;
  // blocked store indices: k0 = oc*L2PAD + pos_base ; u32idx = t*253952 + (k0>>5)*512 + item*8 + ((k0>>2)&7)
  int k0a = r16 * L2PAD + pos_base;
  int k0b = (16 + r16) * L2PAD + pos_base;
  uint32_t sidx0 = (uint32_t)(k0a >> 5) * 512u + (uint32_t)item * 8u + ((uint32_t)(k0a >> 2) & 7u);
  uint32_t sidx1 = (uint32_t)(k0b >> 5) * 512u + (uint32_t)item * 8u + ((uint32_t)(k0b >> 2) & 7u);
  for (int t = 0; t < T_STEPS; ++t) {
    uint2 a0 = na0, a1 = na1;
    const uint8_t* nb = base + (size_t)((t + 1 < T_STEPS) ? t + 1 : t) * 8192;
    na0 = *reinterpret_cast<const uint2*>(nb + off0);
    na1 = *reinterpret_cast<const uint2*>(nb + off1);
    bf16x8 af0 = frag_from_bytes(a0);
    bf16x8 af1 = frag_from_bytes(a1);
    uint32_t st[2];
#pragma unroll
    for (int nt = 0; nt < 2; ++nt) {
      f32x4 acc = (f32x4){0.f, 0.f, 0.f, 0.f};
      acc = __builtin_amdgcn_mfma_f32_16x16x32_bf16(af0, bw[nt][0][0], acc, 0, 0, 0);
      acc = __builtin_amdgcn_mfma_f32_16x16x32_bf16(af1, bw[nt][1][0], acc, 0, 0, 0);
      acc = __builtin_amdgcn_mfma_f32_16x16x32_bf16(af0, bw[nt][0][1], acc, 0, 0, 0);
      acc = __builtin_amdgcn_mfma_f32_16x16x32_bf16(af1, bw[nt][1][1], acc, 0, 0, 0);
      uint32_t packed = 0;
#pragma unroll
      for (int r = 0; r < 4; ++r) {
        float rst = (mem[nt][r] > THR) ? 1.f : 0.f;
        mem[nt][r] = BETA * mem[nt][r] + (acc[r] + sh[nt]) - rst;
        packed |= (mem[nt][r] > THR ? 1u : 0u) << (8 * r);
      }
      st[nt] = packed;
    }
    if (dostore) {
      uint32_t tb = (uint32_t)t * (TSLICE / 4);
      spk2[tb + sidx0] = st[0];
      spk2[tb + sidx1] = st[1];
    }
  }
}

// ---------------- K5: fc1 MFMA GEMM, LDS-free, blocked-A, KSPLIT=16 ----------------
// grid (16, 50), 256 thr = 4 waves; wave wv owns N-cols [wv*64, wv*64+64)
__global__ __launch_bounds__(256) void k_fc1(const uint8_t* __restrict__ spk2,
                                             const uint8_t* __restrict__ wTf,
                                             float* __restrict__ part0,
                                             float* __restrict__ part1) {
  int ks = blockIdx.x;       // 0..15
  int t  = blockIdx.y;       // 0..49
  int tid = threadIdx.x;
  int lane = tid & 63, wv = tid >> 6;
  int r16 = lane & 15, kg = lane >> 4;

  f32x4 acc[4][4];
#pragma unroll
  for (int mi = 0; mi < 4; ++mi)
#pragma unroll
    for (int ni = 0; ni < 4; ++ni) acc[mi][ni] = (f32x4){0.f, 0.f, 0.f, 0.f};

  // A: blocked spk2: t-slice + chunk(ks*31+ch)*2048 + row32*32 + kg*8  (coalesced 512B per instr)
  const uint8_t* abase = spk2 + (size_t)t * TSLICE + (size_t)(ks * KSTEPS) * 2048 + r16 * 32 + kg * 8;
  const uint8_t* bbase = wTf + (size_t)ks * KSTEPS * 32768 + wv * 8192 + lane * 16;

  for (int ch = 0; ch < KSTEPS; ++ch) {
    uint2 a[4];
#pragma unroll
    for (int mi = 0; mi < 4; ++mi)
      a[mi] = *reinterpret_cast<const uint2*>(abase + (size_t)ch * 2048 + mi * 512);
    bf16x8 bfr[4][2];
#pragma unroll
    for (int ni = 0; ni < 4; ++ni)
#pragma unroll
      for (int sel = 0; sel < 2; ++sel)
        bfr[ni][sel] = *reinterpret_cast<const bf16x8*>(bbase + (size_t)ch * 32768 + ni * 2048 + sel * 1024);
    bf16x8 af[4];
#pragma unroll
    for (int mi = 0; mi < 4; ++mi) af[mi] = frag_from_bytes(a[mi]);
#pragma unroll
    for (int ni = 0; ni < 4; ++ni)
#pragma unroll
      for (int mi = 0; mi < 4; ++mi) {
        acc[mi][ni] = __builtin_amdgcn_mfma_f32_16x16x32_bf16(af[mi], bfr[ni][0], acc[mi][ni], 0, 0, 0);
        acc[mi][ni] = __builtin_amdgcn_mfma_f32_16x16x32_bf16(af[mi], bfr[ni][1], acc[mi][ni], 0, 0, 0);
      }
  }
  float* pb = (ks < 8) ? (part0 + (size_t)ks * MROWS * NPAD)
                       : (part1 + (size_t)(ks - 8) * MROWS * NPAD);
  int colb = wv * 64 + r16;
  int rowb = t * 64 + kg * 4;
#pragma unroll
  for (int mi = 0; mi < 4; ++mi)
#pragma unroll
    for (int ni = 0; ni < 4; ++ni) {
      float* pp = pb + (size_t)(rowb + mi * 16) * NPAD + colb + ni * 16;
#pragma unroll
      for (int r = 0; r < 4; ++r) pp[r * NPAD] = acc[mi][ni][r];
    }
}

// ---------------- K6a: reduce 16 K-splits: cur3[3200][256] ----------------
__global__ __launch_bounds__(256) void k_red(const float* __restrict__ part0,
                                             const float* __restrict__ part1,
                                             float* __restrict__ cur3) {
  int i = blockIdx.x * 256 + threadIdx.x;
  float s = 0.f;
#pragma unroll
  for (int ksx = 0; ksx < 8; ++ksx) s += part0[(size_t)ksx * MROWS * NPAD + i];
#pragma unroll
  for (int ksx = 0; ksx < 8; ++ksx) s += part1[(size_t)ksx * MROWS * NPAD + i];
  cur3[i] = s;
}

// ---------------- K6b: fc1 bias + LIF3 + rate/latency -> comb [64][500] ----------------
__global__ __launch_bounds__(256) void k_lif3(const float* __restrict__ cur3,
                                              const float* __restrict__ fc1b,
                                              float* __restrict__ comb) {
  int item = blockIdx.x;
  int n = threadIdx.x;
  if (n >= NFC) return;
  float bias = fc1b[n];
  float sv[T_STEPS];
#pragma unroll
  for (int t = 0; t < T_STEPS; ++t)
    sv[t] = cur3[(size_t)(t * NITEM + item) * NPAD + n];
  float mem = 0.f, cnt = 0.f;
  int first = -1;
#pragma unroll
  for (int t = 0; t < T_STEPS; ++t) {
    float r = (mem > THR) ? 1.f : 0.f;
    mem = BETA * mem + (bias + sv[t]) - r;
    if (mem > THR) { cnt += 1.f; if (first < 0) first = t; }
  }
  comb[item * 500 + n] = cnt;
  comb[item * 500 + NFC + n] = (first < 0) ? 0.f : ((float)first / (float)T_STEPS);
}

// ---------------- K7: head GEMM [64]x[500]->[128] + L2 normalize -> d_out ----------------
__global__ __launch_bounds__(128) void k_head(const float* __restrict__ comb,
                                              const float* __restrict__ fcsw,
                                              const float* __restrict__ fcsb,
                                              float* __restrict__ dout) {
  __shared__ float cr[500];
  __shared__ float red[2];
  int item = blockIdx.x;
  int o = threadIdx.x;
  for (int i = o; i < 500; i += 128) cr[i] = comb[item * 500 + i];
  __syncthreads();
  float acc = fcsb[o];
  for (int j = 0; j < 500; ++j) acc += cr[j] * fcsw[o * 500 + j];
  float sq = acc * acc;
  for (int off = 32; off > 0; off >>= 1) sq += __shfl_down(sq, off, 64);
  if ((o & 63) == 0) red[o >> 6] = sq;
  __syncthreads();
  float norm = sqrtf(red[0] + red[1]);
  norm = fmaxf(norm, 1e-12f);
  dout[item * 128 + o] = acc / norm;
}

// ---------------- launch ----------------
extern "C" void kernel_launch(void* const* d_in, const int* in_sizes, int n_in,
                              void* d_out, int out_size, void* d_ws, size_t ws_size,
                              hipStream_t stream) {
  const float* x1   = (const float*)d_in[0];
  const float* x2   = (const float*)d_in[1];
  const float* c1w  = (const float*)d_in[2];
  const float* c1b  = (const float*)d_in[3];
  const float* bn1g = (const float*)d_in[4];
  const float* bn1b = (const float*)d_in[5];
  const float* bn1m = (const float*)d_in[6];
  const float* bn1v = (const float*)d_in[7];
  const float* c2w  = (const float*)d_in[8];
  const float* c2b  = (const float*)d_in[9];
  const float* bn2g = (const float*)d_in[10];
  const float* bn2b = (const float*)d_in[11];
  const float* bn2m = (const float*)d_in[12];
  const float* bn2v = (const float*)d_in[13];
  const float* fc1w = (const float*)d_in[14];
  const float* fc1b = (const float*)d_in[15];
  const float* fcsw = (const float*)d_in[16];
  const float* fcsb = (const float*)d_in[17];

  char* ws = (char*)d_ws;
  float*    cur1    = (float*)(ws + OFF_CUR1);
  uint8_t*  wfrag   = (uint8_t*)(ws + OFF_CUR1);          // reused AFTER k_lif1
  float*    cur3    = (float*)(ws + OFF_CUR1 + OFF_CUR3); // reused AFTER k_lif1
  uint8_t*  pooledT = (uint8_t*)(ws + OFF_POOL);
  float*    part1   = (float*)(ws + OFF_POOL);            // reused AFTER k_conv2 (slices 8..15)
  uint8_t*  spk2    = (uint8_t*)(ws + OFF_SPK2);
  uint8_t*  wTf     = (uint8_t*)(ws + OFF_WT);
  float*    part0   = (float*)(ws + OFF_PART);
  float*    comb    = (float*)(ws + OFF_COMB);

  k_wt<<<dim3(NKTILE), dim3(256), 0, stream>>>(fc1w, wTf);
  k_conv1<<<dim3(8, NITEM), dim3(256), 0, stream>>>(x1, x2, c1w, c1b, bn1g, bn1b, bn1m, bn1v, cur1);
  k_lif1<<<dim3(8, NITEM), dim3(256), 0, stream>>>(cur1, pooledT);
  k_wc2<<<dim3(1), dim3(512), 0, stream>>>(c2w, c2b, bn2g, bn2b, bn2m, bn2v, wfrag);
  k_conv2<<<dim3(8, NITEM), dim3(256), 0, stream>>>(pooledT, wfrag, (uint32_t*)spk2);
  k_fc1<<<dim3(KSPLIT, T_STEPS), dim3(256), 0, stream>>>(spk2, wTf, part0, part1);
  k_red<<<dim3(MROWS * NPAD / 256), dim3(256), 0, stream>>>(part0, part1, cur3);
  k_lif3<<<dim3(NITEM), dim3(256), 0, stream>>>(cur3, fc1b, comb);
  k_head<<<dim3(NITEM), dim3(128), 0, stream>>>(comb, fcsw, fcsb, (float*)d_out);
}

// Round 8
// 198.707 us; speedup vs baseline: 1.2384x; 1.1048x over previous
//
#include <hip/hip_runtime.h>
#include <math.h>
#include <stdint.h>

// ---------------- dims ----------------
#define BETA 0.9f
#define THR 1.0f
#define T_STEPS 50
#define BN_EPS 1e-5f

#define NITEM 64          // 2 inputs x 32 batch
#define C1 16
#define L1 1981           // conv1 out length
#define L1P 1984          // padded
#define P4 495            // pooled length
#define C2 32
#define L2 493            // conv2 out length
#define L2PAD 496
#define KTOT 15872        // C2*L2PAD (padded flat dim)
#define KREAL 15776       // C2*L2
#define NFC 250
#define NPAD 256
#define KSPLIT 16
#define KRANGE 992        // KTOT/KSPLIT
#define KSTEPS 31         // KRANGE/32
#define NKTILE 496        // KTOT/32
#define MROWS 3200        // T_STEPS*NITEM
#define TSLICE 1015808    // KTOT*64 bytes per t (blocked spk2 slice)

// ---------------- workspace layout (bytes) ----------------
#define OFF_CUR1 0UL
#define OFF_POOL 8126464UL            // 64*16*1984*4
#define OFF_SPK2 34340864UL           // + 26214400 (pooledT; REUSED as part slices 8..15 after conv2)
#define OFF_WT   85131264UL           // + 50790400 (spk2 blocked = 50*TSLICE)
#define OFF_PART 101384192UL          // + 16252928 (wTf)
#define OFF_COMB 127598592UL          // + 8*3200*256*4 (part slices 0..7)
// cur1 region reuse after k_lif1: cur3 at +16384 (3.27 MB)
#define OFF_CUR3 16384UL

typedef __attribute__((ext_vector_type(8))) short bf16x8;
typedef __attribute__((ext_vector_type(4))) float f32x4;

__device__ __forceinline__ uint32_t f32_to_bf16_rne(float f) {
  uint32_t u = __float_as_uint(f);
  return (u + 0x7FFFu + ((u >> 16) & 1u)) >> 16;
}

// spike bytes (bit0) -> 8 bf16 {0,1} in PERMUTED k-order [0,2,1,3,4,6,5,7]
// (B operands are packed in the same order, so the MFMA dot product is unchanged)
__device__ __forceinline__ bf16x8 frag_from_bytes(uint2 a) {
  union { uint32_t u[4]; bf16x8 v; } c;
  c.u[0] = (a.x & 0x00010001u) * 0x3F80u;          // k0,k2
  c.u[1] = ((a.x >> 8) & 0x00010001u) * 0x3F80u;   // k1,k3
  c.u[2] = (a.y & 0x00010001u) * 0x3F80u;          // k4,k6
  c.u[3] = ((a.y >> 8) & 0x00010001u) * 0x3F80u;   // k5,k7
  return c.v;
}

// ---------------- K1: fc1w [250,15776] -> wTf wave-fragment-ready bf16 hi/lo, permuted k-pairs ----------------
// per k-tile (32 k's): [wv(4)][ni(4)][sel(2)][lane(64)][16B] = 32 KB
__global__ __launch_bounds__(256) void k_wt(const float* __restrict__ fc1w,
                                            uint8_t* __restrict__ wTf) {
  int kt = blockIdx.x;        // 0..495
  int n = threadIdx.x;        // 0..255
  int wv = n >> 6, ni = (n >> 4) & 3, r16 = n & 15;
  uint32_t h16[32], l16[32];
#pragma unroll
  for (int kl = 0; kl < 32; ++kl) {
    int k = kt * 32 + kl;
    int oc = k / L2PAD;
    int pos = k - oc * L2PAD;
    float w = 0.f;
    if (pos < L2 && n < NFC) w = fc1w[n * KREAL + oc * L2 + pos];
    uint32_t hb = f32_to_bf16_rne(w);
    float hf = __uint_as_float(hb << 16);
    h16[kl] = hb;
    l16[kl] = f32_to_bf16_rne(w - hf);
  }
  uint8_t* tb = wTf + (size_t)kt * 32768 + wv * 8192 + ni * 2048;
#pragma unroll
  for (int g = 0; g < 4; ++g) {
    int b = g * 8;
    uint4 h;
    h.x = h16[b + 0] | (h16[b + 2] << 16);
    h.y = h16[b + 1] | (h16[b + 3] << 16);
    h.z = h16[b + 4] | (h16[b + 6] << 16);
    h.w = h16[b + 5] | (h16[b + 7] << 16);
    *reinterpret_cast<uint4*>(tb + (g * 16 + r16) * 16) = h;
    uint4 l;
    l.x = l16[b + 0] | (l16[b + 2] << 16);
    l.y = l16[b + 1] | (l16[b + 3] << 16);
    l.z = l16[b + 4] | (l16[b + 6] << 16);
    l.w = l16[b + 5] | (l16[b + 7] << 16);
    *reinterpret_cast<uint4*>(tb + 1024 + (g * 16 + r16) * 16) = l;
  }
}

// ---------------- K2: conv1 (K=80, stride4) + BN1 fold -> cur1 [64][16][1984] ----------------
__global__ __launch_bounds__(256) void k_conv1(const float* __restrict__ x1, const float* __restrict__ x2,
                                               const float* __restrict__ c1w, const float* __restrict__ c1b,
                                               const float* __restrict__ g, const float* __restrict__ bb,
                                               const float* __restrict__ mn, const float* __restrict__ vr,
                                               float* __restrict__ cur1) {
  __shared__ __align__(16) float xs[1104];
  int item = blockIdx.y;
  int pc = blockIdx.x;                 // 0..7
  int tid = threadIdx.x;
  const float* x = (item < 32 ? x1 : x2) + (item & 31) * 8000;
  int xoff = pc * 1024;
  for (int i = tid; i < 1100; i += 256) {
    int gi = xoff + i;
    xs[i] = (gi < 8000) ? x[gi] : 0.f;
  }
  __syncthreads();
  int p = pc * 256 + tid;
  bool pv = (p < L1);
  const float4* xs4 = reinterpret_cast<const float4*>(xs);
  for (int c = 0; c < C1; ++c) {
    float s = g[c] / sqrtf(vr[c] + BN_EPS);
    float sh = (c1b[c] - mn[c]) * s + bb[c];
    const float4* w4 = reinterpret_cast<const float4*>(c1w + c * 80);
    float acc = 0.f;
#pragma unroll
    for (int k4 = 0; k4 < 20; ++k4) {
      float4 wv4 = w4[k4];
      float4 xv = xs4[tid + k4];
      acc += wv4.x * xv.x; acc += wv4.y * xv.y;
      acc += wv4.z * xv.z; acc += wv4.w * xv.w;
    }
    if (pv) cur1[(item * C1 + c) * L1P + p] = acc * s + sh;
  }
}

// ---------------- K3: LIF1 + maxpool4, coalesced u32 stores -> pooled_T [item][t][512][16] ----------------
__global__ __launch_bounds__(256) void k_lif1(const float* __restrict__ cur1,
                                              uint8_t* __restrict__ pooledT) {
  int item = blockIdx.y;
  int g = threadIdx.x & 3;
  int p4 = blockIdx.x * 64 + (threadIdx.x >> 2);
  if (p4 >= P4) return;
  float4 cv[4];
#pragma unroll
  for (int j = 0; j < 4; ++j)
    cv[j] = *reinterpret_cast<const float4*>(cur1 + ((size_t)item * C1 + g * 4 + j) * L1P + 4 * p4);
  float m[4][4];
#pragma unroll
  for (int j = 0; j < 4; ++j)
#pragma unroll
    for (int r = 0; r < 4; ++r) m[j][r] = 0.f;
  uint32_t* out = reinterpret_cast<uint32_t*>(pooledT + ((size_t)item * 50 * 512 + p4) * 16 + g * 4);
  for (int t = 0; t < T_STEPS; ++t) {
    uint32_t pk = 0;
#pragma unroll
    for (int j = 0; j < 4; ++j) {
      int s = 0;
#pragma unroll
      for (int r = 0; r < 4; ++r) {
        float rst = (m[j][r] > THR) ? 1.f : 0.f;
        float cvv = (r == 0) ? cv[j].x : (r == 1) ? cv[j].y : (r == 2) ? cv[j].z : cv[j].w;
        m[j][r] = BETA * m[j][r] + cvv - rst;
        s |= (m[j][r] > THR);
      }
      pk |= ((uint32_t)s) << (8 * j);
    }
    out[t * 2048] = pk;
  }
}

// ---------------- K4: conv2 via MFMA + LIF2, inline weight frags -> spk2 BLOCKED [t][kchunk][item][32B] ----------------
__global__ __launch_bounds__(256) void k_conv2(const uint8_t* __restrict__ pooledT,
                                               const float* __restrict__ c2w, const float* __restrict__ c2b,
                                               const float* __restrict__ g, const float* __restrict__ bb,
                                               const float* __restrict__ mn, const float* __restrict__ vr,
                                               uint32_t* __restrict__ spk2) {
  int item = blockIdx.y;
  int pt = blockIdx.x;
  int tid = threadIdx.x;
  int lane = tid & 63, wv = tid >> 6;
  int r16 = lane & 15, kg = lane >> 4;
  // inline per-lane weight fragments (permuted k-pairs, BN-folded, hi/lo)
  bf16x8 bw[2][2][2];
  float sh[2];
#pragma unroll
  for (int nt = 0; nt < 2; ++nt) {
    int oc = nt * 16 + r16;
    float s2 = g[oc] * rsqrtf(vr[oc] + BN_EPS);
    sh[nt] = (c2b[oc] - mn[oc]) * s2 + bb[oc];
#pragma unroll
    for (int kt = 0; kt < 2; ++kt) {
      uint32_t h[8], l[8];
#pragma unroll
      for (int j = 0; j < 8; ++j) {
        int k = kt * 32 + kg * 8 + j;
        int tap = k >> 4, ic = k & 15;
        float raw = (tap < 3) ? c2w[oc * 48 + ic * 3 + tap] * s2 : 0.f;
        uint32_t hb = f32_to_bf16_rne(raw);
        float hf = __uint_as_float(hb << 16);
        h[j] = hb;
        l[j] = f32_to_bf16_rne(raw - hf);
      }
      union { uint32_t u[4]; bf16x8 v; } ch_, cl_;
      ch_.u[0] = h[0] | (h[2] << 16); ch_.u[1] = h[1] | (h[3] << 16);
      ch_.u[2] = h[4] | (h[6] << 16); ch_.u[3] = h[5] | (h[7] << 16);
      cl_.u[0] = l[0] | (l[2] << 16); cl_.u[1] = l[1] | (l[3] << 16);
      cl_.u[2] = l[4] | (l[6] << 16); cl_.u[3] = l[5] | (l[7] << 16);
      bw[nt][kt][0] = ch_.v;
      bw[nt][kt][1] = cl_.v;
    }
  }
  const uint8_t* base = pooledT + (size_t)item * 50 * 8192;
  int rowA = pt * 64 + wv * 16 + r16;
  size_t off0 = (size_t)(rowA + (kg >> 1)) * 16 + 8 * (kg & 1);   // taps 0/1
  size_t off1 = (size_t)(rowA + 2) * 16 + 8 * (kg & 1);           // tap 2 (+pad)
  uint2 na0 = *reinterpret_cast<const uint2*>(base + off0);
  uint2 na1 = *reinterpret_cast<const uint2*>(base + off1);
  float mem[2][4] = {{0.f, 0.f, 0.f, 0.f}, {0.f, 0.f, 0.f, 0.f}};
  int pos_base = pt * 64 + wv * 16 + kg * 4;
  bool dostore = pos_base < L2PAD;
  // blocked store indices: k0 = oc*L2PAD + pos_base ; u32idx = (k0>>5)*512 + item*8 + ((k0>>2)&7)
  int k0a = r16 * L2PAD + pos_base;
  int k0b = (16 + r16) * L2PAD + pos_base;
  uint32_t sidx0 = (uint32_t)(k0a >> 5) * 512u + (uint32_t)item * 8u + ((uint32_t)(k0a >> 2) & 7u);
  uint32_t sidx1 = (uint32_t)(k0b >> 5) * 512u + (uint32_t)item * 8u + ((uint32_t)(k0b >> 2) & 7u);
  for (int t = 0; t < T_STEPS; ++t) {
    uint2 a0 = na0, a1 = na1;
    const uint8_t* nb = base + (size_t)((t + 1 < T_STEPS) ? t + 1 : t) * 8192;
    na0 = *reinterpret_cast<const uint2*>(nb + off0);
    na1 = *reinterpret_cast<const uint2*>(nb + off1);
    bf16x8 af0 = frag_from_bytes(a0);
    bf16x8 af1 = frag_from_bytes(a1);
    uint32_t st[2];
#pragma unroll
    for (int nt = 0; nt < 2; ++nt) {
      f32x4 acc = (f32x4){0.f, 0.f, 0.f, 0.f};
      acc = __builtin_amdgcn_mfma_f32_16x16x32_bf16(af0, bw[nt][0][0], acc, 0, 0, 0);
      acc = __builtin_amdgcn_mfma_f32_16x16x32_bf16(af1, bw[nt][1][0], acc, 0, 0, 0);
      acc = __builtin_amdgcn_mfma_f32_16x16x32_bf16(af0, bw[nt][0][1], acc, 0, 0, 0);
      acc = __builtin_amdgcn_mfma_f32_16x16x32_bf16(af1, bw[nt][1][1], acc, 0, 0, 0);
      uint32_t packed = 0;
#pragma unroll
      for (int r = 0; r < 4; ++r) {
        float rst = (mem[nt][r] > THR) ? 1.f : 0.f;
        mem[nt][r] = BETA * mem[nt][r] + (acc[r] + sh[nt]) - rst;
        packed |= (mem[nt][r] > THR ? 1u : 0u) << (8 * r);
      }
      st[nt] = packed;
    }
    if (dostore) {
      uint32_t tb = (uint32_t)t * (TSLICE / 4);
      spk2[tb + sidx0] = st[0];
      spk2[tb + sidx1] = st[1];
    }
  }
}

// ---------------- K5: fc1 MFMA GEMM, LDS-free, blocked-A, M=128 via 8 waves ----------------
// grid (16 ks, 25 mt), 512 thr = 8 waves; wave = (mg, wv): mg picks t=2mt+mg, wv picks N-cols
// both mg groups load IDENTICAL B addresses -> L1/L2-local reuse halves B traffic
__global__ __launch_bounds__(512) void k_fc1(const uint8_t* __restrict__ spk2,
                                             const uint8_t* __restrict__ wTf,
                                             float* __restrict__ part0,
                                             float* __restrict__ part1) {
  int ks = blockIdx.x;       // 0..15
  int mt = blockIdx.y;       // 0..24
  int tid = threadIdx.x;
  int lane = tid & 63, w8 = tid >> 6;
  int wv = w8 & 3, mg = w8 >> 2;
  int r16 = lane & 15, kg = lane >> 4;
  int t = mt * 2 + mg;

  f32x4 acc[4][4];
#pragma unroll
  for (int mi = 0; mi < 4; ++mi)
#pragma unroll
    for (int ni = 0; ni < 4; ++ni) acc[mi][ni] = (f32x4){0.f, 0.f, 0.f, 0.f};

  const uint8_t* abase = spk2 + (size_t)t * TSLICE + (size_t)(ks * KSTEPS) * 2048 + r16 * 32 + kg * 8;
  const uint8_t* bbase = wTf + (size_t)ks * KSTEPS * 32768 + wv * 8192 + lane * 16;

  for (int ch = 0; ch < KSTEPS; ++ch) {
    uint2 a[4];
#pragma unroll
    for (int mi = 0; mi < 4; ++mi)
      a[mi] = *reinterpret_cast<const uint2*>(abase + (size_t)ch * 2048 + mi * 512);
    bf16x8 bfr[4][2];
#pragma unroll
    for (int ni = 0; ni < 4; ++ni)
#pragma unroll
      for (int sel = 0; sel < 2; ++sel)
        bfr[ni][sel] = *reinterpret_cast<const bf16x8*>(bbase + (size_t)ch * 32768 + ni * 2048 + sel * 1024);
    bf16x8 af[4];
#pragma unroll
    for (int mi = 0; mi < 4; ++mi) af[mi] = frag_from_bytes(a[mi]);
#pragma unroll
    for (int ni = 0; ni < 4; ++ni)
#pragma unroll
      for (int mi = 0; mi < 4; ++mi) {
        acc[mi][ni] = __builtin_amdgcn_mfma_f32_16x16x32_bf16(af[mi], bfr[ni][0], acc[mi][ni], 0, 0, 0);
        acc[mi][ni] = __builtin_amdgcn_mfma_f32_16x16x32_bf16(af[mi], bfr[ni][1], acc[mi][ni], 0, 0, 0);
      }
  }
  float* pb = (ks < 8) ? (part0 + (size_t)ks * MROWS * NPAD)
                       : (part1 + (size_t)(ks - 8) * MROWS * NPAD);
  int colb = wv * 64 + r16;
  int rowb = t * 64 + kg * 4;
#pragma unroll
  for (int mi = 0; mi < 4; ++mi)
#pragma unroll
    for (int ni = 0; ni < 4; ++ni) {
      float* pp = pb + (size_t)(rowb + mi * 16) * NPAD + colb + ni * 16;
#pragma unroll
      for (int r = 0; r < 4; ++r) pp[r * NPAD] = acc[mi][ni][r];
    }
}

// ---------------- K6a: reduce 16 K-splits: cur3[3200][256] ----------------
__global__ __launch_bounds__(256) void k_red(const float* __restrict__ part0,
                                             const float* __restrict__ part1,
                                             float* __restrict__ cur3) {
  int i = blockIdx.x * 256 + threadIdx.x;
  float s = 0.f;
#pragma unroll
  for (int ksx = 0; ksx < 8; ++ksx) s += part0[(size_t)ksx * MROWS * NPAD + i];
#pragma unroll
  for (int ksx = 0; ksx < 8; ++ksx) s += part1[(size_t)ksx * MROWS * NPAD + i];
  cur3[i] = s;
}

// ---------------- K6b: fc1 bias + LIF3 + rate/latency -> comb [64][500] ----------------
__global__ __launch_bounds__(256) void k_lif3(const float* __restrict__ cur3,
                                              const float* __restrict__ fc1b,
                                              float* __restrict__ comb) {
  int item = blockIdx.x;
  int n = threadIdx.x;
  if (n >= NFC) return;
  float bias = fc1b[n];
  float sv[T_STEPS];
#pragma unroll
  for (int t = 0; t < T_STEPS; ++t)
    sv[t] = cur3[(size_t)(t * NITEM + item) * NPAD + n];
  float mem = 0.f, cnt = 0.f;
  int first = -1;
#pragma unroll
  for (int t = 0; t < T_STEPS; ++t) {
    float r = (mem > THR) ? 1.f : 0.f;
    mem = BETA * mem + (bias + sv[t]) - r;
    if (mem > THR) { cnt += 1.f; if (first < 0) first = t; }
  }
  comb[item * 500 + n] = cnt;
  comb[item * 500 + NFC + n] = (first < 0) ? 0.f : ((float)first / (float)T_STEPS);
}

// ---------------- K7: head GEMM [64]x[500]->[128] + L2 normalize -> d_out ----------------
__global__ __launch_bounds__(128) void k_head(const float* __restrict__ comb,
                                              const float* __restrict__ fcsw,
                                              const float* __restrict__ fcsb,
                                              float* __restrict__ dout) {
  __shared__ float cr[500];
  __shared__ float red[2];
  int item = blockIdx.x;
  int o = threadIdx.x;
  for (int i = o; i < 500; i += 128) cr[i] = comb[item * 500 + i];
  __syncthreads();
  float acc = fcsb[o];
  for (int j = 0; j < 500; ++j) acc += cr[j] * fcsw[o * 500 + j];
  float sq = acc * acc;
  for (int off = 32; off > 0; off >>= 1) sq += __shfl_down(sq, off, 64);
  if ((o & 63) == 0) red[o >> 6] = sq;
  __syncthreads();
  float norm = sqrtf(red[0] + red[1]);
  norm = fmaxf(norm, 1e-12f);
  dout[item * 128 + o] = acc / norm;
}

// ---------------- launch ----------------
extern "C" void kernel_launch(void* const* d_in, const int* in_sizes, int n_in,
                              void* d_out, int out_size, void* d_ws, size_t ws_size,
                              hipStream_t stream) {
  const float* x1   = (const float*)d_in[0];
  const float* x2   = (const float*)d_in[1];
  const float* c1w  = (const float*)d_in[2];
  const float* c1b  = (const float*)d_in[3];
  const float* bn1g = (const float*)d_in[4];
  const float* bn1b = (const float*)d_in[5];
  const float* bn1m = (const float*)d_in[6];
  const float* bn1v = (const float*)d_in[7];
  const float* c2w  = (const float*)d_in[8];
  const float* c2b  = (const float*)d_in[9];
  const float* bn2g = (const float*)d_in[10];
  const float* bn2b = (const float*)d_in[11];
  const float* bn2m = (const float*)d_in[12];
  const float* bn2v = (const float*)d_in[13];
  const float* fc1w = (const float*)d_in[14];
  const float* fc1b = (const float*)d_in[15];
  const float* fcsw = (const float*)d_in[16];
  const float* fcsb = (const float*)d_in[17];

  char* ws = (char*)d_ws;
  float*    cur1    = (float*)(ws + OFF_CUR1);
  float*    cur3    = (float*)(ws + OFF_CUR1 + OFF_CUR3); // reused AFTER k_lif1
  uint8_t*  pooledT = (uint8_t*)(ws + OFF_POOL);
  float*    part1   = (float*)(ws + OFF_POOL);            // reused AFTER k_conv2 (slices 8..15)
  uint8_t*  spk2    = (uint8_t*)(ws + OFF_SPK2);
  uint8_t*  wTf     = (uint8_t*)(ws + OFF_WT);
  float*    part0   = (float*)(ws + OFF_PART);
  float*    comb    = (float*)(ws + OFF_COMB);

  k_wt<<<dim3(NKTILE), dim3(256), 0, stream>>>(fc1w, wTf);
  k_conv1<<<dim3(8, NITEM), dim3(256), 0, stream>>>(x1, x2, c1w, c1b, bn1g, bn1b, bn1m, bn1v, cur1);
  k_lif1<<<dim3(8, NITEM), dim3(256), 0, stream>>>(cur1, pooledT);
  k_conv2<<<dim3(8, NITEM), dim3(256), 0, stream>>>(pooledT, c2w, c2b, bn2g, bn2b, bn2m, bn2v,
                                                    (uint32_t*)spk2);
  k_fc1<<<dim3(KSPLIT, T_STEPS / 2), dim3(512), 0, stream>>>(spk2, wTf, part0, part1);
  k_red<<<dim3(MROWS * NPAD / 256), dim3(256), 0, stream>>>(part0, part1, cur3);
  k_lif3<<<dim3(NITEM), dim3(256), 0, stream>>>(cur3, fc1b, comb);
  k_head<<<dim3(NITEM), dim3(128), 0, stream>>>(comb, fcsw, fcsb, (float*)d_out);
}